// Round 2
// baseline (326.358 us; speedup 1.0000x reference)
//
#include <hip/hip_runtime.h>

#define D_DIM 4096
#define EPSF 1e-8f

// Fused: one block per row computes cos[row]; the last block to finish
// performs the deterministic label-split reduction and writes the loss.
// d_ws layout: [0,4) counter (uint), [256, 256+B*4) cos values.
__global__ __launch_bounds__(256) void cosim_fused(const float* __restrict__ q,
                                                   const float* __restrict__ a,
                                                   const int* __restrict__ label,
                                                   const float* __restrict__ margin,
                                                   float* __restrict__ cosv,
                                                   unsigned int* __restrict__ counter,
                                                   float* __restrict__ out, int B) {
    const int row = blockIdx.x;
    const int t = threadIdx.x;
    const float4* q4 = reinterpret_cast<const float4*>(q + (size_t)row * D_DIM);
    const float4* a4 = reinterpret_cast<const float4*>(a + (size_t)row * D_DIM);

    // Issue all 8 loads up-front -> 8 outstanding global_load_dwordx4 per wave.
    float4 vq0 = q4[t];
    float4 va0 = a4[t];
    float4 vq1 = q4[t + 256];
    float4 va1 = a4[t + 256];
    float4 vq2 = q4[t + 512];
    float4 va2 = a4[t + 512];
    float4 vq3 = q4[t + 768];
    float4 va3 = a4[t + 768];

    float dot = 0.f, qq = 0.f, aa = 0.f;
    dot += vq0.x * va0.x + vq0.y * va0.y + vq0.z * va0.z + vq0.w * va0.w;
    qq  += vq0.x * vq0.x + vq0.y * vq0.y + vq0.z * vq0.z + vq0.w * vq0.w;
    aa  += va0.x * va0.x + va0.y * va0.y + va0.z * va0.z + va0.w * va0.w;
    dot += vq1.x * va1.x + vq1.y * va1.y + vq1.z * va1.z + vq1.w * va1.w;
    qq  += vq1.x * vq1.x + vq1.y * vq1.y + vq1.z * vq1.z + vq1.w * vq1.w;
    aa  += va1.x * va1.x + va1.y * va1.y + va1.z * va1.z + va1.w * va1.w;
    dot += vq2.x * va2.x + vq2.y * va2.y + vq2.z * va2.z + vq2.w * va2.w;
    qq  += vq2.x * vq2.x + vq2.y * vq2.y + vq2.z * vq2.z + vq2.w * vq2.w;
    aa  += va2.x * va2.x + va2.y * va2.y + va2.z * va2.z + va2.w * va2.w;
    dot += vq3.x * va3.x + vq3.y * va3.y + vq3.z * va3.z + vq3.w * va3.w;
    qq  += vq3.x * vq3.x + vq3.y * vq3.y + vq3.z * vq3.z + vq3.w * vq3.w;
    aa  += va3.x * va3.x + va3.y * va3.y + va3.z * va3.z + va3.w * va3.w;

#pragma unroll
    for (int off = 32; off > 0; off >>= 1) {
        dot += __shfl_down(dot, off, 64);
        qq  += __shfl_down(qq,  off, 64);
        aa  += __shfl_down(aa,  off, 64);
    }

    __shared__ float s[3][4];
    __shared__ bool amLast;
    const int wave = t >> 6;
    if ((t & 63) == 0) { s[0][wave] = dot; s[1][wave] = qq; s[2][wave] = aa; }
    __syncthreads();
    if (t == 0) {
        float d   = s[0][0] + s[0][1] + s[0][2] + s[0][3];
        float qsq = s[1][0] + s[1][1] + s[1][2] + s[1][3];
        float asq = s[2][0] + s[2][1] + s[2][2] + s[2][3];
        float qn = fmaxf(sqrtf(qsq), EPSF);
        float an = fmaxf(sqrtf(asq), EPSF);
        cosv[row] = d / (qn * an);
        __threadfence();                       // release cos[row] device-wide
        unsigned int old = atomicAdd(counter, 1u);
        amLast = (old == (unsigned int)(gridDim.x - 1));
    }
    __syncthreads();

    if (amLast) {
        __threadfence();                       // acquire all blocks' cos writes
        float ts = 0.f, fs = 0.f, tc = 0.f, fc = 0.f;
        for (int i = t; i < B; i += 256) {
            float c = cosv[i];
            int l = label[i];
            if (l == 1)       { ts += c; tc += 1.f; }
            else if (l == -1) { fs += c; fc += 1.f; }
        }
#pragma unroll
        for (int off = 32; off > 0; off >>= 1) {
            ts += __shfl_down(ts, off, 64);
            fs += __shfl_down(fs, off, 64);
            tc += __shfl_down(tc, off, 64);
            fc += __shfl_down(fc, off, 64);
        }
        __shared__ float r[4][4];
        if ((t & 63) == 0) { r[0][wave] = ts; r[1][wave] = fs; r[2][wave] = tc; r[3][wave] = fc; }
        __syncthreads();
        if (t == 0) {
            float tsum = r[0][0] + r[0][1] + r[0][2] + r[0][3];
            float fsum = r[1][0] + r[1][1] + r[1][2] + r[1][3];
            float tcnt = r[2][0] + r[2][1] + r[2][2] + r[2][3];
            float fcnt = r[3][0] + r[3][1] + r[3][2] + r[3][3];
            out[0] = fmaxf(0.f, margin[0] - tsum / tcnt + fsum / fcnt);
        }
    }
}

extern "C" void kernel_launch(void* const* d_in, const int* in_sizes, int n_in,
                              void* d_out, int out_size, void* d_ws, size_t ws_size,
                              hipStream_t stream) {
    const float* ques   = (const float*)d_in[0];
    const float* ans    = (const float*)d_in[1];
    const int*   label  = (const int*)d_in[2];
    const float* margin = (const float*)d_in[3];
    float* out = (float*)d_out;

    const int B = in_sizes[2];                              // 8192 rows
    unsigned int* counter = (unsigned int*)d_ws;            // [0,4)
    float* cosv = (float*)((char*)d_ws + 256);              // [256, 256+B*4)

    hipMemsetAsync(counter, 0, sizeof(unsigned int), stream);
    cosim_fused<<<B, 256, 0, stream>>>(ques, ans, label, margin, cosv, counter, out, B);
}

// Round 4
// 61.690 us; speedup vs baseline: 5.2902x; 5.2902x over previous
//
#include <hip/hip_runtime.h>

#define D_DIM 4096
#define EPSF 1e-8f

typedef float f32x4 __attribute__((ext_vector_type(4)));

// One WAVE per row: 64 lanes x 16 float4 = 4096 floats per tensor per row.
// No __syncthreads, no LDS in the hot path -> no vmcnt drains; every wave is
// an independent coalesced stream (1 KB per load instruction).
__global__ __launch_bounds__(256) void cosim_rows(const float* __restrict__ q,
                                                  const float* __restrict__ a,
                                                  float* __restrict__ cosv) {
    const int row  = (blockIdx.x * 256 + threadIdx.x) >> 6;   // global wave id
    const int lane = threadIdx.x & 63;

    const f32x4* q4 = reinterpret_cast<const f32x4*>(q + (size_t)row * D_DIM);
    const f32x4* a4 = reinterpret_cast<const f32x4*>(a + (size_t)row * D_DIM);

    float dot = 0.f, qq = 0.f, aa = 0.f;
#pragma unroll
    for (int k = 0; k < 16; ++k) {
        f32x4 vq = q4[lane + k * 64];
        f32x4 va = a4[lane + k * 64];
        dot += vq.x * va.x + vq.y * va.y + vq.z * va.z + vq.w * va.w;
        qq  += vq.x * vq.x + vq.y * vq.y + vq.z * vq.z + vq.w * vq.w;
        aa  += va.x * va.x + va.y * va.y + va.z * va.z + va.w * va.w;
    }

    // wave64 down-reduce; lane 0 holds the row sums
#pragma unroll
    for (int off = 32; off > 0; off >>= 1) {
        dot += __shfl_down(dot, off, 64);
        qq  += __shfl_down(qq,  off, 64);
        aa  += __shfl_down(aa,  off, 64);
    }

    if (lane == 0) {
        float qn = fmaxf(sqrtf(qq), EPSF);
        float an = fmaxf(sqrtf(aa), EPSF);
        cosv[row] = dot / (qn * an);
    }
}

// Single block: deterministic fixed-order reduction of cos values by label.
__global__ __launch_bounds__(256) void cosim_finalize(const float* __restrict__ cosv,
                                                      const int* __restrict__ label,
                                                      const float* __restrict__ margin,
                                                      float* __restrict__ out, int B) {
    const int t = threadIdx.x;
    float ts = 0.f, fs = 0.f, tc = 0.f, fc = 0.f;
    for (int i = t; i < B; i += 256) {
        float c = cosv[i];
        int l = label[i];
        if (l == 1)       { ts += c; tc += 1.f; }
        else if (l == -1) { fs += c; fc += 1.f; }
    }
#pragma unroll
    for (int off = 32; off > 0; off >>= 1) {
        ts += __shfl_down(ts, off, 64);
        fs += __shfl_down(fs, off, 64);
        tc += __shfl_down(tc, off, 64);
        fc += __shfl_down(fc, off, 64);
    }
    __shared__ float s[4][4];
    const int wave = t >> 6;
    if ((t & 63) == 0) { s[0][wave] = ts; s[1][wave] = fs; s[2][wave] = tc; s[3][wave] = fc; }
    __syncthreads();
    if (t == 0) {
        float tsum = s[0][0] + s[0][1] + s[0][2] + s[0][3];
        float fsum = s[1][0] + s[1][1] + s[1][2] + s[1][3];
        float tcnt = s[2][0] + s[2][1] + s[2][2] + s[2][3];
        float fcnt = s[3][0] + s[3][1] + s[3][2] + s[3][3];
        out[0] = fmaxf(0.f, margin[0] - tsum / tcnt + fsum / fcnt);
    }
}

extern "C" void kernel_launch(void* const* d_in, const int* in_sizes, int n_in,
                              void* d_out, int out_size, void* d_ws, size_t ws_size,
                              hipStream_t stream) {
    const float* ques   = (const float*)d_in[0];
    const float* ans    = (const float*)d_in[1];
    const int*   label  = (const int*)d_in[2];
    const float* margin = (const float*)d_in[3];
    float* out = (float*)d_out;

    const int B = in_sizes[2];          // 8192 rows
    float* cosv = (float*)d_ws;         // B floats of scratch

    // 1 wave per row: 8192 waves / 4 waves per 256-thread block = 2048 blocks
    cosim_rows<<<B / 4, 256, 0, stream>>>(ques, ans, cosv);
    cosim_finalize<<<1, 256, 0, stream>>>(cosv, label, margin, out, B);
}